// Round 9
// baseline (144.524 us; speedup 1.0000x reference)
//
#include <hip/hip_runtime.h>
#include <stdint.h>

// MultiHeadAttention fused pipeline for MI355X (gfx950).
// B=2, T=2048, C=1024, H=16, Dh=64. All inputs fp32; compute in bf16 MFMA.
//
// ws layout (48 MiB):
//   [ 0MB) xb   : x as bf16            [4096][1024]
//   [ 8MB) Wqt  : Wq^T bf16            [1024 n][1024 k]
//   [10MB) Wkt, [12MB) Wvt, [14MB) Wpt
//   [16MB) Qb   : [32 head][2048 t][64 d] bf16  (PRE-SCALED by 0.125*log2e)
//   [24MB) Kb   : same layout (unscaled)
//   [32MB) Vb   : TRANSPOSED [32 head][64 d][2048 t] bf16
//   [40MB) Ab   : attention out [4096 row=b*T+t][1024 col=h*64+d] bf16

typedef unsigned short bfu;                               // bf16 bits
typedef unsigned int u32;
typedef short bf16x8 __attribute__((ext_vector_type(8))); // 8 bf16 (4 VGPRs)
typedef float f32x4 __attribute__((ext_vector_type(4)));
typedef float f32x16 __attribute__((ext_vector_type(16)));

#define DEVI static __device__ __forceinline__

DEVI bfu f2bf(float f) {  // round-to-nearest-even fp32 -> bf16 bits
  union { float f; unsigned u; } a; a.f = f;
  unsigned u = a.u;
  u += 0x7fffu + ((u >> 16) & 1u);
  return (bfu)(u >> 16);
}

DEVI void gld_lds16(const void* g, void* l) {
  __builtin_amdgcn_global_load_lds(
      (const __attribute__((address_space(1))) void*)g,
      (__attribute__((address_space(3))) void*)l, 16, 0, 0);
}

// counted-vmcnt barrier (T4): only the OLDEST stages must be complete; the
// newest stays in flight across the barrier. Memory-clobber asm brackets the
// raw s_barrier so the scheduler can't move memory ops across it.
#define BAR_VM4()                                         \
  do {                                                    \
    asm volatile("s_waitcnt vmcnt(4)" ::: "memory");      \
    __builtin_amdgcn_s_barrier();                         \
    asm volatile("" ::: "memory");                        \
  } while (0)
#define BAR_VM0()                                         \
  do {                                                    \
    asm volatile("s_waitcnt vmcnt(0)" ::: "memory");      \
    __builtin_amdgcn_s_barrier();                         \
    asm volatile("" ::: "memory");                        \
  } while (0)

// ---------------- prep kernels ----------------

__global__ __launch_bounds__(256) void conv_x(const float* __restrict__ x,
                                              bfu* __restrict__ xb) {
  const int n4 = (4096 * 1024) / 4;
  for (int i = blockIdx.x * 256 + threadIdx.x; i < n4; i += gridDim.x * 256) {
    float4 v = ((const float4*)x)[i];
    ushort4 p;
    p.x = f2bf(v.x); p.y = f2bf(v.y); p.z = f2bf(v.z); p.w = f2bf(v.w);
    ((ushort4*)xb)[i] = p;
  }
}

// convert + transpose a 1024x1024 fp32 [k][n] -> bf16 [n][k]
__global__ __launch_bounds__(256) void conv_w(
    const float* __restrict__ W0, const float* __restrict__ W1,
    const float* __restrict__ W2, const float* __restrict__ W3,
    bfu* __restrict__ T0, bfu* __restrict__ T1,
    bfu* __restrict__ T2, bfu* __restrict__ T3) {
  __shared__ bfu tile[64][65];
  const float* W; bfu* T;
  switch (blockIdx.z) {
    case 0:  W = W0; T = T0; break;
    case 1:  W = W1; T = T1; break;
    case 2:  W = W2; T = T2; break;
    default: W = W3; T = T3; break;
  }
  const int k0 = blockIdx.y * 64, n0 = blockIdx.x * 64;
  const int c = threadIdx.x & 63, r4 = threadIdx.x >> 6;
#pragma unroll
  for (int i = 0; i < 16; i++) {
    int row = r4 + i * 4;  // k-local
    tile[row][c] = f2bf(W[(size_t)(k0 + row) * 1024 + n0 + c]);
  }
  __syncthreads();
#pragma unroll
  for (int i = 0; i < 16; i++) {
    int row = r4 + i * 4;  // n-local
    T[(size_t)(n0 + row) * 1024 + k0 + c] = tile[c][row];
  }
}

// ------- GEMM core v4: TRIPLE-buffer, counted vmcnt(4), raw s_barrier (T4) -------
// C[M,N] = A[M,K] * Bt[N,K]^T, bf16 row-major. 256 threads = 4 waves (2x2).
// As/Bs are [3][4096] (48 KB total). Stage(i+2) issued at step i; barrier waits
// only vmcnt(4) -> stage(i+1) complete, stage(i+2) stays in flight (never drain
// to 0 in the loop). T2 slot swizzle kept (conflicts measured 0).

DEVI void gemm128_core(const bfu* __restrict__ A, const bfu* __restrict__ Bt,
                       int K, int m0, int n0, bfu* As, bfu* Bs, int tid,
                       f32x4 acc[4][4]) {
  const int lane = tid & 63, wave = tid >> 6;
  const int wr = wave >> 1, wc = wave & 1;
  const int fr = lane & 15, fq = lane >> 4;
  const int r_a = tid >> 2;          // 0..63 staging row
  // T2 swizzle: LDS slot (tid&3) of row (tid>>2) <- global slot ^((row>>1)&3)
  const int koff = ((tid & 3) ^ ((tid >> 3) & 3)) * 8;   // bf16 units
  const int rslot = (fq ^ ((fr >> 1) & 3)) * 8;          // read-side swizzle
#define GSTAGE(buf, k0s)                                                              \
  do {                                                                                \
    gld_lds16(A  + (size_t)(m0 +      r_a) * K + (k0s) + koff,                        \
              As + (buf) * 4096 + tid * 8);                                           \
    gld_lds16(A  + (size_t)(m0 + 64 + r_a) * K + (k0s) + koff,                        \
              As + (buf) * 4096 + 2048 + tid * 8);                                    \
    gld_lds16(Bt + (size_t)(n0 +      r_a) * K + (k0s) + koff,                        \
              Bs + (buf) * 4096 + tid * 8);                                           \
    gld_lds16(Bt + (size_t)(n0 + 64 + r_a) * K + (k0s) + koff,                        \
              Bs + (buf) * 4096 + 2048 + tid * 8);                                    \
  } while (0)
  const int NS = K >> 5;             // 32-wide K-steps (NS >= 2)
  GSTAGE(0, 0);
  GSTAGE(1, 32);
  BAR_VM4();                          // stage0 done; stage1 in flight
  for (int i = 0; i < NS; i++) {
    if (i + 2 < NS) GSTAGE((i + 2) % 3, (i + 2) * 32);
    const bfu* AsC = As + (i % 3) * 4096;
    const bfu* BsC = Bs + (i % 3) * 4096;
    bf16x8 af[4], bfv[4];
#pragma unroll
    for (int m = 0; m < 4; m++)
      af[m] = *(const bf16x8*)&AsC[(wr * 64 + m * 16 + fr) * 32 + rslot];
#pragma unroll
    for (int n = 0; n < 4; n++)
      bfv[n] = *(const bf16x8*)&BsC[(wc * 64 + n * 16 + fr) * 32 + rslot];
#pragma unroll
    for (int m = 0; m < 4; m++)
#pragma unroll
      for (int n = 0; n < 4; n++)
        acc[m][n] = __builtin_amdgcn_mfma_f32_16x16x32_bf16(af[m], bfv[n],
                                                            acc[m][n], 0, 0, 0);
    if (i + 2 < NS) BAR_VM4();        // next stage done, newest in flight
    else            BAR_VM0();        // tail: drain
  }
#undef GSTAGE
}

// QKV projection: z=0 -> Q (pre-scaled), z=1 -> K, z=2 -> V transposed
__global__ __launch_bounds__(256) void gemm_qkv(
    const bfu* __restrict__ A, const bfu* __restrict__ Wqt,
    const bfu* __restrict__ Wkt, const bfu* __restrict__ Wvt,
    bfu* __restrict__ Qb, bfu* __restrict__ Kb, bfu* __restrict__ Vb) {
  __shared__ __align__(16) bfu As[3 * 4096];
  __shared__ __align__(16) bfu Bs[3 * 4096];
  const bfu* Bt; bfu* out; int epi;
  if (blockIdx.z == 0)      { Bt = Wqt; out = Qb; epi = 0; }
  else if (blockIdx.z == 1) { Bt = Wkt; out = Kb; epi = 0; }
  else                      { Bt = Wvt; out = Vb; epi = 1; }
  const float qs = (blockIdx.z == 0) ? 0.1803368801f : 1.0f;  // 0.125*log2e
  const int m0 = blockIdx.y * 128, n0 = blockIdx.x * 128;
  const int tid = threadIdx.x, lane = tid & 63, wave = tid >> 6;
  const int wr = wave >> 1, wc = wave & 1, fr = lane & 15, fq = lane >> 4;
  f32x4 acc[4][4] = {};
  gemm128_core(A, Bt, 1024, m0, n0, As, Bs, tid, acc);
#pragma unroll
  for (int m = 0; m < 4; m++)
#pragma unroll
    for (int n = 0; n < 4; n++) {
      int r = m0 + wr * 64 + m * 16 + fq * 4;  // global row (b*2048+t), +i
      int c = n0 + wc * 64 + n * 16 + fr;      // global col (h*64+d)
      int b = r >> 11, t = r & 2047, h = c >> 6, d = c & 63;
      if (epi == 0) {
        size_t base = ((size_t)(b * 16 + h) * 2048 + t) * 64 + d;
#pragma unroll
        for (int i = 0; i < 4; i++)
          out[base + (size_t)i * 64] = f2bf(acc[m][n][i] * qs);
      } else {
        size_t base = ((size_t)(b * 16 + h) * 64 + d) * 2048 + t;
        ushort4 p;
        p.x = f2bf(acc[m][n][0]); p.y = f2bf(acc[m][n][1]);
        p.z = f2bf(acc[m][n][2]); p.w = f2bf(acc[m][n][3]);
        *(ushort4*)&out[base] = p;  // 4 consecutive t -> contiguous
      }
    }
}

// output projection: out[4096][1024] fp32 = Ab @ Wpt^T + bias
__global__ __launch_bounds__(256) void gemm_proj(
    const bfu* __restrict__ A, const bfu* __restrict__ Bt,
    const float* __restrict__ bias, float* __restrict__ out) {
  __shared__ __align__(16) bfu As[3 * 4096];
  __shared__ __align__(16) bfu Bs[3 * 4096];
  const int m0 = blockIdx.y * 128, n0 = blockIdx.x * 128;
  const int tid = threadIdx.x, lane = tid & 63, wave = tid >> 6;
  const int wr = wave >> 1, wc = wave & 1, fr = lane & 15, fq = lane >> 4;
  f32x4 acc[4][4] = {};
  gemm128_core(A, Bt, 1024, m0, n0, As, Bs, tid, acc);
#pragma unroll
  for (int m = 0; m < 4; m++)
#pragma unroll
    for (int n = 0; n < 4; n++) {
      int r = m0 + wr * 64 + m * 16 + fq * 4;
      int c = n0 + wc * 64 + n * 16 + fr;
      float bv = bias[c];
#pragma unroll
      for (int i = 0; i < 4; i++)
        out[(size_t)(r + i) * 1024 + c] = acc[m][n][i] + bv;
    }
}

// -------- flash attention (causal) v7: r3 math + triple-buffer counted vmcnt --------
// 512 WGs: (head-instance, q-block of 128 rows). 4 waves x 32 q-rows, KVBLK=64.
// S^T = mfma(K, Q); in-register softmax; P->A-frag via cvt_pk+permlane (T12);
// l via MFMA-ones; defer-max (T13). K/V now TRIPLE-buffered, stage(kb+2) issued
// at step kb, barriers wait vmcnt(4) only (T4) — never drain in the loop.

__global__ __launch_bounds__(256) void attn_fwd(
    const bfu* __restrict__ Q, const bfu* __restrict__ K,
    const bfu* __restrict__ Vt, bfu* __restrict__ Ob) {
  __shared__ __align__(16) bfu Ks[3][4096];   // 8 KB each buf (64 rows x 64)
  __shared__ __align__(16) bfu Vs[3][4096];
  const int bid = blockIdx.x;
  const int xcd = bid & 7, idx = bid >> 3;       // idx 0..63
  const int hb = xcd * 4 + (idx & 3);            // head instance (= b*16+h)
  const int rank = idx >> 2;                     // 0..15
  const int qb = (rank < 8) ? (15 - rank) : (rank - 8);  // balanced pairing
  const int tid = threadIdx.x, wave = tid >> 6, lane = tid & 63;
  const int q31 = lane & 31, hi = lane >> 5;
  const bfu* Qh = Q  + (size_t)hb * 2048 * 64;
  const bfu* Kh = K  + (size_t)hb * 2048 * 64;
  const bfu* Vh = Vt + (size_t)hb * 64 * 2048;
  const int b = hb >> 4, h = hb & 15;
  const int q0w = qb * 128 + wave * 32;          // this wave's 32 q rows
  const int kbmax = 2 * qb + 1;                  // >= 1 always
  const int qg = q0w + q31;

  // staging: 512 x 16B slots per tile; slot s -> row = s>>3, col-slot s&7 holds
  // global col-group (s&7) ^ (row&7) (XOR involution, linear LDS dest).
  const int r0 = tid >> 3, r1 = (256 + tid) >> 3;
  const int c0 = (tid & 7) ^ (r0 & 7), c1 = (tid & 7) ^ (r1 & 7);
#define STAGE(bufi, kbase)                                                            \
  do {                                                                                \
    gld_lds16(Kh + (size_t)((kbase) + r0) * 64 + c0 * 8, &Ks[bufi][tid * 8]);         \
    gld_lds16(Kh + (size_t)((kbase) + r1) * 64 + c1 * 8, &Ks[bufi][(256 + tid) * 8]); \
    gld_lds16(Vh + (size_t)r0 * 2048 + (kbase) + c0 * 8, &Vs[bufi][tid * 8]);         \
    gld_lds16(Vh + (size_t)r1 * 2048 + (kbase) + c1 * 8, &Vs[bufi][(256 + tid) * 8]); \
  } while (0)

  // Q as B-frags (4 d-chunks): B[d=8*hi+j][q=lane&31]
  bf16x8 qv[4];
#pragma unroll
  for (int c = 0; c < 4; c++)
    qv[c] = *(const bf16x8*)&Qh[(size_t)(q0w + q31) * 64 + c * 16 + hi * 8];

  bf16x8 onesv;
#pragma unroll
  for (int j = 0; j < 8; j++) onesv[j] = (short)0x3F80;  // bf16 1.0

  f32x16 o0 = {}, o1 = {}, lac = {};
  float m = -1e30f;

  STAGE(0, 0);
  STAGE(1, 64);
  BAR_VM4();                          // tile0 ready; tile1 in flight

  for (int kb = 0; kb <= kbmax; kb++) {
    const int cur = kb % 3;
    const int more = (kb + 2 <= kbmax);
    if (more) STAGE((kb + 2) % 3, (kb + 2) * 64);   // 2-ahead prefetch
    const int kbase = kb * 64;
    if (kbase <= q0w + 31) {                         // wave has unmasked work
      const bfu* KsC = Ks[cur];
      const bfu* VsC = Vs[cur];
      // S^T = K . Q^T : rows k (reg map), cols q (lane&31)
      f32x16 s0 = {}, s1 = {};
#pragma unroll
      for (int c = 0; c < 4; c++) {
        const int g = 2 * c + hi;
        bf16x8 kf0 = *(const bf16x8*)&KsC[(q31 * 8 + (g ^ (q31 & 7))) * 8];
        bf16x8 kf1 = *(const bf16x8*)&KsC[((32 + q31) * 8 + (g ^ (q31 & 7))) * 8];
        s0 = __builtin_amdgcn_mfma_f32_32x32x16_bf16(kf0, qv[c], s0, 0, 0, 0);
        s1 = __builtin_amdgcn_mfma_f32_32x32x16_bf16(kf1, qv[c], s1, 0, 0, 0);
      }
      if (kbase + 63 > q0w) {  // tile crosses diagonal: causal mask
#pragma unroll
        for (int r = 0; r < 16; r++) {
          int krow = (r & 3) + 8 * (r >> 2) + 4 * hi;
          if (kbase + krow > qg)      s0[r] = -1e30f;
          if (kbase + 32 + krow > qg) s1[r] = -1e30f;
        }
      }
      // row max: 31 local fmax + one cross-half swap
      float pm = s0[0];
#pragma unroll
      for (int r = 1; r < 16; r++) pm = fmaxf(pm, s0[r]);
#pragma unroll
      for (int r = 0; r < 16; r++) pm = fmaxf(pm, s1[r]);
      pm = fmaxf(pm, __shfl_xor(pm, 32));
      // defer-max (T13): rescale only when max grows > 8 (exp2 domain)
      if (!__all(pm <= m + 8.0f)) {
        float mn = fmaxf(m, pm);
        float al = __builtin_amdgcn_exp2f(m - mn);
        m = mn;
#pragma unroll
        for (int r = 0; r < 16; r++) {
          float alq = __shfl(al, (r & 3) + 8 * (r >> 2) + 4 * hi);
          o0[r] *= alq; o1[r] *= alq; lac[r] *= alq;
        }
      }
      // p = exp2(s - m); pack pairs to bf16 words (16 cvt_pk)
      u32 W0[8], W1[8];
#pragma unroll
      for (int w = 0; w < 8; w++) {
        float a0 = __builtin_amdgcn_exp2f(s0[2 * w] - m);
        float a1 = __builtin_amdgcn_exp2f(s0[2 * w + 1] - m);
        asm("v_cvt_pk_bf16_f32 %0, %1, %2" : "=v"(W0[w]) : "v"(a0), "v"(a1));
        float b0 = __builtin_amdgcn_exp2f(s1[2 * w] - m);
        float b1 = __builtin_amdgcn_exp2f(s1[2 * w + 1] - m);
        asm("v_cvt_pk_bf16_f32 %0, %1, %2" : "=v"(W1[w]) : "v"(b0), "v"(b1));
      }
      // PV + l, per 16-k chunk: A-frag via 2 permlane32_swap per chunk (T12)
      __builtin_amdgcn_s_setprio(1);
#pragma unroll
      for (int c = 0; c < 4; c++) {
        const u32* Wsel = (c < 2) ? W0 : W1;
        const int w0 = 4 * (c & 1);
        u32 t0 = Wsel[w0],     t2 = Wsel[w0 + 2];
        u32 t1 = Wsel[w0 + 1], t3 = Wsel[w0 + 3];
        asm("v_permlane32_swap_b32 %0, %1" : "+v"(t0), "+v"(t2));
        asm("v_permlane32_swap_b32 %0, %1" : "+v"(t1), "+v"(t3));
        union { u32 u[4]; bf16x8 v; } pa;
        pa.u[0] = t0; pa.u[1] = t1; pa.u[2] = t2; pa.u[3] = t3;
        const int g = 2 * c + hi;
        bf16x8 vb0 = *(const bf16x8*)&VsC[(q31 * 8 + (g ^ (q31 & 7))) * 8];
        bf16x8 vb1 = *(const bf16x8*)&VsC[((32 + q31) * 8 + (g ^ (q31 & 7))) * 8];
        o0  = __builtin_amdgcn_mfma_f32_32x32x16_bf16(pa.v, vb0,   o0,  0, 0, 0);
        o1  = __builtin_amdgcn_mfma_f32_32x32x16_bf16(pa.v, vb1,   o1,  0, 0, 0);
        lac = __builtin_amdgcn_mfma_f32_32x32x16_bf16(pa.v, onesv, lac, 0, 0, 0);
      }
      __builtin_amdgcn_s_setprio(0);
    }
    if (more) BAR_VM4();   // next tile ready; newest prefetch stays in flight
    else      BAR_VM0();   // tail: drain
  }
#undef STAGE

  // epilogue: Ob[b*2048+t][h*64+d]; o layout: col d = lane&31 (+32), row q = reg map
#pragma unroll
  for (int r = 0; r < 16; r++) {
    int t = q0w + (r & 3) + 8 * (r >> 2) + 4 * hi;
    float inv = 1.0f / lac[r];
    size_t base = (size_t)(b * 2048 + t) * 1024 + h * 64;
    Ob[base + q31]      = f2bf(o0[r] * inv);
    Ob[base + 32 + q31] = f2bf(o1[r] * inv);
  }
}

// ---------------- launch ----------------

extern "C" void kernel_launch(void* const* d_in, const int* in_sizes, int n_in,
                              void* d_out, int out_size, void* d_ws, size_t ws_size,
                              hipStream_t stream) {
  const float* x  = (const float*)d_in[0];
  const float* Wk = (const float*)d_in[1];  // note dict order: Wk before Wq!
  const float* Wq = (const float*)d_in[2];
  const float* Wv = (const float*)d_in[3];
  const float* Wp = (const float*)d_in[4];
  const float* bp = (const float*)d_in[5];
  char* ws = (char*)d_ws;
  bfu* xb  = (bfu*)(ws);
  bfu* Wqt = (bfu*)(ws + ( 8u << 20));
  bfu* Wkt = (bfu*)(ws + (10u << 20));
  bfu* Wvt = (bfu*)(ws + (12u << 20));
  bfu* Wpt = (bfu*)(ws + (14u << 20));
  bfu* Qb  = (bfu*)(ws + (16u << 20));
  bfu* Kb  = (bfu*)(ws + (24u << 20));
  bfu* Vb  = (bfu*)(ws + (32u << 20));
  bfu* Ab  = (bfu*)(ws + (40u << 20));
  float* out = (float*)d_out;

  conv_x<<<1024, 256, 0, stream>>>(x, xb);
  conv_w<<<dim3(16, 16, 4), 256, 0, stream>>>(Wq, Wk, Wv, Wp, Wqt, Wkt, Wvt, Wpt);
  gemm_qkv<<<dim3(8, 32, 3), 256, 0, stream>>>(xb, Wqt, Wkt, Wvt, Qb, Kb, Vb);
  attn_fwd<<<512, 256, 0, stream>>>(Qb, Kb, Vb, Ab);
  gemm_proj<<<dim3(8, 32), 256, 0, stream>>>(Ab, Wpt, bp, out);
}

// Round 11
// 138.737 us; speedup vs baseline: 1.0417x; 1.0417x over previous
//
#include <hip/hip_runtime.h>
#include <stdint.h>

// MultiHeadAttention fused pipeline for MI355X (gfx950).
// B=2, T=2048, C=1024, H=16, Dh=64. All inputs fp32; compute in bf16 MFMA.
//
// ws layout (48 MiB):
//   [ 0MB) xb   : x as bf16            [4096][1024]
//   [ 8MB) Wqt  : Wq^T bf16            [1024 n][1024 k]
//   [10MB) Wkt, [12MB) Wvt, [14MB) Wpt
//   [16MB) Qb   : [32 head][2048 t][64 d] bf16  (PRE-SCALED by 0.125*log2e)
//   [24MB) Kb   : same layout (unscaled)
//   [32MB) Vb   : TRANSPOSED [32 head][64 d][2048 t] bf16
//   [40MB) Ab   : attention out [4096 row=b*T+t][1024 col=h*64+d] bf16

typedef unsigned short bfu;                               // bf16 bits
typedef unsigned int u32;
typedef short bf16x8 __attribute__((ext_vector_type(8))); // 8 bf16 (4 VGPRs)
typedef float f32x4 __attribute__((ext_vector_type(4)));
typedef float f32x16 __attribute__((ext_vector_type(16)));

#define DEVI static __device__ __forceinline__

DEVI bfu f2bf(float f) {  // round-to-nearest-even fp32 -> bf16 bits
  union { float f; unsigned u; } a; a.f = f;
  unsigned u = a.u;
  u += 0x7fffu + ((u >> 16) & 1u);
  return (bfu)(u >> 16);
}

DEVI void gld_lds16(const void* g, void* l) {
  __builtin_amdgcn_global_load_lds(
      (const __attribute__((address_space(1))) void*)g,
      (__attribute__((address_space(3))) void*)l, 16, 0, 0);
}

// counted-vmcnt barrier (T4) for the GEMM core.
#define BAR_VM4()                                         \
  do {                                                    \
    asm volatile("s_waitcnt vmcnt(4)" ::: "memory");      \
    __builtin_amdgcn_s_barrier();                         \
    asm volatile("" ::: "memory");                        \
  } while (0)
#define BAR_VM0()                                         \
  do {                                                    \
    asm volatile("s_waitcnt vmcnt(0)" ::: "memory");      \
    __builtin_amdgcn_s_barrier();                         \
    asm volatile("" ::: "memory");                        \
  } while (0)

// ---------------- prep kernels ----------------

__global__ __launch_bounds__(256) void conv_x(const float* __restrict__ x,
                                              bfu* __restrict__ xb) {
  const int n4 = (4096 * 1024) / 4;
  for (int i = blockIdx.x * 256 + threadIdx.x; i < n4; i += gridDim.x * 256) {
    float4 v = ((const float4*)x)[i];
    ushort4 p;
    p.x = f2bf(v.x); p.y = f2bf(v.y); p.z = f2bf(v.z); p.w = f2bf(v.w);
    ((ushort4*)xb)[i] = p;
  }
}

// convert + transpose a 1024x1024 fp32 [k][n] -> bf16 [n][k]
__global__ __launch_bounds__(256) void conv_w(
    const float* __restrict__ W0, const float* __restrict__ W1,
    const float* __restrict__ W2, const float* __restrict__ W3,
    bfu* __restrict__ T0, bfu* __restrict__ T1,
    bfu* __restrict__ T2, bfu* __restrict__ T3) {
  __shared__ bfu tile[64][65];
  const float* W; bfu* T;
  switch (blockIdx.z) {
    case 0:  W = W0; T = T0; break;
    case 1:  W = W1; T = T1; break;
    case 2:  W = W2; T = T2; break;
    default: W = W3; T = T3; break;
  }
  const int k0 = blockIdx.y * 64, n0 = blockIdx.x * 64;
  const int c = threadIdx.x & 63, r4 = threadIdx.x >> 6;
#pragma unroll
  for (int i = 0; i < 16; i++) {
    int row = r4 + i * 4;  // k-local
    tile[row][c] = f2bf(W[(size_t)(k0 + row) * 1024 + n0 + c]);
  }
  __syncthreads();
#pragma unroll
  for (int i = 0; i < 16; i++) {
    int row = r4 + i * 4;  // n-local
    T[(size_t)(n0 + row) * 1024 + k0 + c] = tile[c][row];
  }
}

// ------- GEMM core (r9-proven): TRIPLE-buffer, counted vmcnt(4), raw s_barrier -------

DEVI void gemm128_core(const bfu* __restrict__ A, const bfu* __restrict__ Bt,
                       int K, int m0, int n0, bfu* As, bfu* Bs, int tid,
                       f32x4 acc[4][4]) {
  const int lane = tid & 63, wave = tid >> 6;
  const int wr = wave >> 1, wc = wave & 1;
  const int fr = lane & 15, fq = lane >> 4;
  const int r_a = tid >> 2;          // 0..63 staging row
  const int koff = ((tid & 3) ^ ((tid >> 3) & 3)) * 8;   // T2 swizzled source slot
  const int rslot = (fq ^ ((fr >> 1) & 3)) * 8;          // read-side swizzle
#define GSTAGE(buf, k0s)                                                              \
  do {                                                                                \
    gld_lds16(A  + (size_t)(m0 +      r_a) * K + (k0s) + koff,                        \
              As + (buf) * 4096 + tid * 8);                                           \
    gld_lds16(A  + (size_t)(m0 + 64 + r_a) * K + (k0s) + koff,                        \
              As + (buf) * 4096 + 2048 + tid * 8);                                    \
    gld_lds16(Bt + (size_t)(n0 +      r_a) * K + (k0s) + koff,                        \
              Bs + (buf) * 4096 + tid * 8);                                           \
    gld_lds16(Bt + (size_t)(n0 + 64 + r_a) * K + (k0s) + koff,                        \
              Bs + (buf) * 4096 + 2048 + tid * 8);                                    \
  } while (0)
  const int NS = K >> 5;             // 32-wide K-steps (NS >= 2)
  GSTAGE(0, 0);
  GSTAGE(1, 32);
  BAR_VM4();                          // stage0 done; stage1 in flight
  for (int i = 0; i < NS; i++) {
    if (i + 2 < NS) GSTAGE((i + 2) % 3, (i + 2) * 32);
    const bfu* AsC = As + (i % 3) * 4096;
    const bfu* BsC = Bs + (i % 3) * 4096;
    bf16x8 af[4], bfv[4];
#pragma unroll
    for (int m = 0; m < 4; m++)
      af[m] = *(const bf16x8*)&AsC[(wr * 64 + m * 16 + fr) * 32 + rslot];
#pragma unroll
    for (int n = 0; n < 4; n++)
      bfv[n] = *(const bf16x8*)&BsC[(wc * 64 + n * 16 + fr) * 32 + rslot];
#pragma unroll
    for (int m = 0; m < 4; m++)
#pragma unroll
      for (int n = 0; n < 4; n++)
        acc[m][n] = __builtin_amdgcn_mfma_f32_16x16x32_bf16(af[m], bfv[n],
                                                            acc[m][n], 0, 0, 0);
    if (i + 2 < NS) BAR_VM4();        // next stage done, newest in flight
    else            BAR_VM0();        // tail: drain
  }
#undef GSTAGE
}

// QKV projection, T1 XCD-aware 1-D grid (768 blocks): all 24 blocks sharing an
// A m-panel land on ONE XCD -> panel fetched once into that XCD's L2.
// decode: xcd=bid%8, i=bid/8 (0..95): tz=i/32, rem=i%32, tx=rem>>2, ty=xcd*4+(rem&3)
__global__ __launch_bounds__(256) void gemm_qkv(
    const bfu* __restrict__ A, const bfu* __restrict__ Wqt,
    const bfu* __restrict__ Wkt, const bfu* __restrict__ Wvt,
    bfu* __restrict__ Qb, bfu* __restrict__ Kb, bfu* __restrict__ Vb) {
  __shared__ __align__(16) bfu As[3 * 4096];
  __shared__ __align__(16) bfu Bs[3 * 4096];
  const int bid = blockIdx.x;
  const int xcd = bid & 7, i0 = bid >> 3;        // i0 0..95
  const int tz = i0 >> 5, rem = i0 & 31;
  const int tx = rem >> 2, ty = xcd * 4 + (rem & 3);
  const bfu* Bt; bfu* out; int epi;
  if (tz == 0)      { Bt = Wqt; out = Qb; epi = 0; }
  else if (tz == 1) { Bt = Wkt; out = Kb; epi = 0; }
  else              { Bt = Wvt; out = Vb; epi = 1; }
  const float qs = (tz == 0) ? 0.1803368801f : 1.0f;  // 0.125*log2e
  const int m0 = ty * 128, n0 = tx * 128;
  const int tid = threadIdx.x, lane = tid & 63, wave = tid >> 6;
  const int wr = wave >> 1, wc = wave & 1, fr = lane & 15, fq = lane >> 4;
  f32x4 acc[4][4] = {};
  gemm128_core(A, Bt, 1024, m0, n0, As, Bs, tid, acc);
#pragma unroll
  for (int m = 0; m < 4; m++)
#pragma unroll
    for (int n = 0; n < 4; n++) {
      int r = m0 + wr * 64 + m * 16 + fq * 4;  // global row (b*2048+t), +i
      int c = n0 + wc * 64 + n * 16 + fr;      // global col (h*64+d)
      int b = r >> 11, t = r & 2047, h = c >> 6, d = c & 63;
      if (epi == 0) {
        size_t base = ((size_t)(b * 16 + h) * 2048 + t) * 64 + d;
#pragma unroll
        for (int i = 0; i < 4; i++)
          out[base + (size_t)i * 64] = f2bf(acc[m][n][i] * qs);
      } else {
        size_t base = ((size_t)(b * 16 + h) * 64 + d) * 2048 + t;
        ushort4 p;
        p.x = f2bf(acc[m][n][0]); p.y = f2bf(acc[m][n][1]);
        p.z = f2bf(acc[m][n][2]); p.w = f2bf(acc[m][n][3]);
        *(ushort4*)&out[base] = p;  // 4 consecutive t -> contiguous
      }
    }
}

// output projection, T1 XCD-aware 1-D grid (256 blocks):
// decode: xcd=bid%8, i=bid/8 (0..31): tx=i>>2, ty=xcd*4+(i&3)
__global__ __launch_bounds__(256) void gemm_proj(
    const bfu* __restrict__ A, const bfu* __restrict__ Bt,
    const float* __restrict__ bias, float* __restrict__ out) {
  __shared__ __align__(16) bfu As[3 * 4096];
  __shared__ __align__(16) bfu Bs[3 * 4096];
  const int bid = blockIdx.x;
  const int xcd = bid & 7, i0 = bid >> 3;        // i0 0..31
  const int tx = i0 >> 2, ty = xcd * 4 + (i0 & 3);
  const int m0 = ty * 128, n0 = tx * 128;
  const int tid = threadIdx.x, lane = tid & 63, wave = tid >> 6;
  const int wr = wave >> 1, wc = wave & 1, fr = lane & 15, fq = lane >> 4;
  f32x4 acc[4][4] = {};
  gemm128_core(A, Bt, 1024, m0, n0, As, Bs, tid, acc);
#pragma unroll
  for (int m = 0; m < 4; m++)
#pragma unroll
    for (int n = 0; n < 4; n++) {
      int r = m0 + wr * 64 + m * 16 + fq * 4;
      int c = n0 + wc * 64 + n * 16 + fr;
      float bv = bias[c];
#pragma unroll
      for (int i = 0; i < 4; i++)
        out[(size_t)(r + i) * 1024 + c] = acc[m][n][i] + bv;
    }
}

// ---------------- flash attention (causal), r8 bench-proven source ----------------
// 512 WGs: (head-instance, q-block of 128 rows). 4 waves x 32 q-rows, KVBLK=64.
// S^T = mfma(K, Q): lane holds P half-row for q=lane&31 -> in-register softmax.
// P->A-frag via cvt_pk_bf16 + permlane32_swap (T12). l via MFMA-ones (acc layout).
// Defer-max rescale (T13, THR=8). K/V dbuf LDS, XOR-swizzled.

__global__ __launch_bounds__(256) void attn_fwd(
    const bfu* __restrict__ Q, const bfu* __restrict__ K,
    const bfu* __restrict__ Vt, bfu* __restrict__ Ob) {
  __shared__ __align__(16) bfu Ks[2][64 * 64];   // 8 KB each buf
  __shared__ __align__(16) bfu Vs[2][64 * 64];
  const int bid = blockIdx.x;
  const int xcd = bid & 7, idx = bid >> 3;       // idx 0..63
  const int hb = xcd * 4 + (idx & 3);            // head instance (= b*16+h)
  const int rank = idx >> 2;                     // 0..15
  const int qb = (rank < 8) ? (15 - rank) : (rank - 8);  // balanced pairing
  const int tid = threadIdx.x, wave = tid >> 6, lane = tid & 63;
  const int q31 = lane & 31, hi = lane >> 5;
  const bfu* Qh = Q  + (size_t)hb * 2048 * 64;
  const bfu* Kh = K  + (size_t)hb * 2048 * 64;
  const bfu* Vh = Vt + (size_t)hb * 64 * 2048;
  const int b = hb >> 4, h = hb & 15;
  const int q0w = qb * 128 + wave * 32;          // this wave's 32 q rows
  const int kbmax = 2 * qb + 1;
  const int qg = q0w + q31;

  // staging: 512 x 16B slots per tile; slot s -> row = s>>3, col-slot s&7 holds
  // global col-group (s&7) ^ (row&7) (XOR involution, linear LDS dest).
  const int r0 = tid >> 3, r1 = (256 + tid) >> 3;
  const int c0 = (tid & 7) ^ (r0 & 7), c1 = (tid & 7) ^ (r1 & 7);
#define STAGE(bufi, kbase)                                                            \
  do {                                                                                \
    gld_lds16(Kh + (size_t)((kbase) + r0) * 64 + c0 * 8, &Ks[bufi][tid * 8]);         \
    gld_lds16(Kh + (size_t)((kbase) + r1) * 64 + c1 * 8, &Ks[bufi][(256 + tid) * 8]); \
    gld_lds16(Vh + (size_t)r0 * 2048 + (kbase) + c0 * 8, &Vs[bufi][tid * 8]);         \
    gld_lds16(Vh + (size_t)r1 * 2048 + (kbase) + c1 * 8, &Vs[bufi][(256 + tid) * 8]); \
  } while (0)

  // Q as B-frags (4 d-chunks): B[d=8*hi+j][q=lane&31]
  bf16x8 qv[4];
#pragma unroll
  for (int c = 0; c < 4; c++)
    qv[c] = *(const bf16x8*)&Qh[(size_t)(q0w + q31) * 64 + c * 16 + hi * 8];

  bf16x8 onesv;
#pragma unroll
  for (int j = 0; j < 8; j++) onesv[j] = (short)0x3F80;  // bf16 1.0

  f32x16 o0 = {}, o1 = {}, lac = {};
  float m = -1e30f;

  STAGE(0, 0);
  __syncthreads();

  for (int kb = 0; kb <= kbmax; kb++) {
    const int cur = kb & 1;
    if (kb < kbmax) STAGE(cur ^ 1, (kb + 1) * 64);   // issue next tile early
    const int kbase = kb * 64;
    if (kbase <= q0w + 31) {                         // wave has unmasked work
      const bfu* KsC = Ks[cur];
      const bfu* VsC = Vs[cur];
      // S^T = K . Q^T : rows k (reg map), cols q (lane&31)
      f32x16 s0 = {}, s1 = {};
#pragma unroll
      for (int c = 0; c < 4; c++) {
        const int g = 2 * c + hi;
        bf16x8 kf0 = *(const bf16x8*)&KsC[(q31 * 8 + (g ^ (q31 & 7))) * 8];
        bf16x8 kf1 = *(const bf16x8*)&KsC[((32 + q31) * 8 + (g ^ (q31 & 7))) * 8];
        s0 = __builtin_amdgcn_mfma_f32_32x32x16_bf16(kf0, qv[c], s0, 0, 0, 0);
        s1 = __builtin_amdgcn_mfma_f32_32x32x16_bf16(kf1, qv[c], s1, 0, 0, 0);
      }
      if (kbase + 63 > q0w) {  // tile crosses diagonal: causal mask
#pragma unroll
        for (int r = 0; r < 16; r++) {
          int krow = (r & 3) + 8 * (r >> 2) + 4 * hi;
          if (kbase + krow > qg)      s0[r] = -1e30f;
          if (kbase + 32 + krow > qg) s1[r] = -1e30f;
        }
      }
      // row max: 31 local fmax + one cross-half swap
      float pm = s0[0];
#pragma unroll
      for (int r = 1; r < 16; r++) pm = fmaxf(pm, s0[r]);
#pragma unroll
      for (int r = 0; r < 16; r++) pm = fmaxf(pm, s1[r]);
      pm = fmaxf(pm, __shfl_xor(pm, 32));
      // defer-max (T13): rescale only when max grows > 8 (exp2 domain)
      if (!__all(pm <= m + 8.0f)) {
        float mn = fmaxf(m, pm);
        float al = __builtin_amdgcn_exp2f(m - mn);
        m = mn;
#pragma unroll
        for (int r = 0; r < 16; r++) {
          float alq = __shfl(al, (r & 3) + 8 * (r >> 2) + 4 * hi);
          o0[r] *= alq; o1[r] *= alq; lac[r] *= alq;
        }
      }
      // p = exp2(s - m); pack pairs to bf16 words (16 cvt_pk)
      u32 W0[8], W1[8];
#pragma unroll
      for (int w = 0; w < 8; w++) {
        float a0 = __builtin_amdgcn_exp2f(s0[2 * w] - m);
        float a1 = __builtin_amdgcn_exp2f(s0[2 * w + 1] - m);
        asm("v_cvt_pk_bf16_f32 %0, %1, %2" : "=v"(W0[w]) : "v"(a0), "v"(a1));
        float b0 = __builtin_amdgcn_exp2f(s1[2 * w] - m);
        float b1 = __builtin_amdgcn_exp2f(s1[2 * w + 1] - m);
        asm("v_cvt_pk_bf16_f32 %0, %1, %2" : "=v"(W1[w]) : "v"(b0), "v"(b1));
      }
      // PV + l, per 16-k chunk: A-frag via 2 permlane32_swap per chunk (T12)
      __builtin_amdgcn_s_setprio(1);
#pragma unroll
      for (int c = 0; c < 4; c++) {
        const u32* Wsel = (c < 2) ? W0 : W1;
        const int w0 = 4 * (c & 1);
        u32 t0 = Wsel[w0],     t2 = Wsel[w0 + 2];
        u32 t1 = Wsel[w0 + 1], t3 = Wsel[w0 + 3];
        asm("v_permlane32_swap_b32 %0, %1" : "+v"(t0), "+v"(t2));
        asm("v_permlane32_swap_b32 %0, %1" : "+v"(t1), "+v"(t3));
        union { u32 u[4]; bf16x8 v; } pa;
        pa.u[0] = t0; pa.u[1] = t1; pa.u[2] = t2; pa.u[3] = t3;
        const int g = 2 * c + hi;
        bf16x8 vb0 = *(const bf16x8*)&VsC[(q31 * 8 + (g ^ (q31 & 7))) * 8];
        bf16x8 vb1 = *(const bf16x8*)&VsC[((32 + q31) * 8 + (g ^ (q31 & 7))) * 8];
        o0  = __builtin_amdgcn_mfma_f32_32x32x16_bf16(pa.v, vb0,   o0,  0, 0, 0);
        o1  = __builtin_amdgcn_mfma_f32_32x32x16_bf16(pa.v, vb1,   o1,  0, 0, 0);
        lac = __builtin_amdgcn_mfma_f32_32x32x16_bf16(pa.v, onesv, lac, 0, 0, 0);
      }
      __builtin_amdgcn_s_setprio(0);
    }
    __syncthreads();  // drains staged loads + guards buffer reuse
  }
#undef STAGE

  // epilogue: Ob[b*2048+t][h*64+d]; o layout: col d = lane&31 (+32), row q = reg map
#pragma unroll
  for (int r = 0; r < 16; r++) {
    int t = q0w + (r & 3) + 8 * (r >> 2) + 4 * hi;
    float inv = 1.0f / lac[r];
    size_t base = (size_t)(b * 2048 + t) * 1024 + h * 64;
    Ob[base + q31]      = f2bf(o0[r] * inv);
    Ob[base + 32 + q31] = f2bf(o1[r] * inv);
  }
}

// ---------------- launch ----------------

extern "C" void kernel_launch(void* const* d_in, const int* in_sizes, int n_in,
                              void* d_out, int out_size, void* d_ws, size_t ws_size,
                              hipStream_t stream) {
  const float* x  = (const float*)d_in[0];
  const float* Wk = (const float*)d_in[1];  // note dict order: Wk before Wq!
  const float* Wq = (const float*)d_in[2];
  const float* Wv = (const float*)d_in[3];
  const float* Wp = (const float*)d_in[4];
  const float* bp = (const float*)d_in[5];
  char* ws = (char*)d_ws;
  bfu* xb  = (bfu*)(ws);
  bfu* Wqt = (bfu*)(ws + ( 8u << 20));
  bfu* Wkt = (bfu*)(ws + (10u << 20));
  bfu* Wvt = (bfu*)(ws + (12u << 20));
  bfu* Wpt = (bfu*)(ws + (14u << 20));
  bfu* Qb  = (bfu*)(ws + (16u << 20));
  bfu* Kb  = (bfu*)(ws + (24u << 20));
  bfu* Vb  = (bfu*)(ws + (32u << 20));
  bfu* Ab  = (bfu*)(ws + (40u << 20));
  float* out = (float*)d_out;

  conv_x<<<1024, 256, 0, stream>>>(x, xb);
  conv_w<<<dim3(16, 16, 4), 256, 0, stream>>>(Wq, Wk, Wv, Wp, Wqt, Wkt, Wvt, Wpt);
  gemm_qkv<<<768, 256, 0, stream>>>(xb, Wqt, Wkt, Wvt, Qb, Kb, Vb);
  attn_fwd<<<512, 256, 0, stream>>>(Qb, Kb, Vb, Ab);
  gemm_proj<<<256, 256, 0, stream>>>(Ab, Wpt, bp, out);
}